// Round 1
// baseline (4642.222 us; speedup 1.0000x reference)
//
// Phi_Layer_joint_opt: factored kron GEMM. fp32 inputs (runtime-sniffed, bf16
// fallback), FP32 outputs (float2 per complex), fp32 internal math.
//
// Nt=Nr=64, Mt=Mr=32, G^2=4096, S=32, B=64, R=8, N_r_RF=4.
// Phi[(mt,mr),g]  = sum_nt F[nt,mt] * ( sum_nr conjW[nr,mr] * K2[nt*64+nr, g] )
// y[b,(mt,mr),s]  = sum_nt F[nt,mt] * T[b,mr,nt,s]  +  eff[b,mr,mt*32+s]
//   T[b,mr,nt,s]  = sum_nr conjW[nr,mr] * H[b,nr,nt,s]      (fused in uy_kernel)
//   eff[b,mr,x]   = sum_nr conjW[nr,mr] * noise[b,mr>>2,nr,x] (written to y out)
//
// ws floats: [0,4096) conjW {re,im}; [4096,8192) F {re,im}; [8192] dtype flag.
//
// v2 (this round): phi_kernel restructured — 512-thread blocks with nt split
// across two 256-thread halves (16 waves/CU vs 8), reg-prefetched double-
// buffered K2 tile (1 barrier/iter, load latency hidden), float2 LDS reads,
// LDS-based cross-half reduction (no atomics). eff_kernel: distance-2 load
// pipeline. uy_kernel unchanged.
#include <hip/hip_runtime.h>
#include <hip/hip_bf16.h>

typedef unsigned short u16;
typedef unsigned int u32;

#define WS_CONJW 0
#define WS_F     4096
#define WS_FLAG  8192

__device__ __forceinline__ float bfb2f(u16 b){
  union { u32 u; float f; } v; v.u = ((u32)b) << 16; return v.f;
}
// complex load at pair-index i, dtype selected by wave-uniform flag
__device__ __forceinline__ float2 ldc(const void* p, long i, bool bf){
  if (bf){ ushort2 v = ((const ushort2*)p)[i]; return make_float2(bfb2f(v.x), bfb2f(v.y)); }
  return ((const float2*)p)[i];
}
// two complex (float4) at pair-index i
__device__ __forceinline__ float4 ldc2(const void* p, long i, bool bf){
  if (bf){ ushort4 v = *(const ushort4*)((const u16*)p + 2*i);
           return make_float4(bfb2f(v.x), bfb2f(v.y), bfb2f(v.z), bfb2f(v.w)); }
  return *(const float4*)((const float*)p + 2*i);
}
__device__ __forceinline__ float lds1(const void* p, int i, bool bf){
  return bf ? bfb2f(((const u16*)p)[i]) : ((const float*)p)[i];
}
// Sniff kernel_W storage dtype. bf16 normals: low u16 of each u32 has bf16
// exponent (bits 14:7) ~101..129 for N(0,1). fp32: those bits are uniform
// mantissa bits -> ~16% in range. 64 samples, threshold 48. 256 B in-bounds.
__device__ __forceinline__ bool detect_bf16(const void* kW){
  const u32* p = (const u32*)kW;
  int hits = 0;
  for (int i = 0; i < 64; ++i){
    int e = (p[i] >> 7) & 0xFF;
    hits += (e >= 100 && e <= 140) ? 1 : 0;
  }
  return hits >= 48;
}

// ---- kernel 1: phases -> conjW, F (fp32 in ws) + dtype flag ---------------
__global__ void wf_kernel(const void* __restrict__ kW, const void* __restrict__ kF,
                          float* __restrict__ ws){
  const bool bf = detect_bf16(kW);
  int t = blockIdx.x * 256 + threadIdx.x;
  if (t == 0) ws[WS_FLAG] = bf ? 1.0f : 0.0f;
  if (t < 2048){
    float w = lds1(kW, t, bf);
    ws[WS_CONJW + 2*t]     =  cosf(w) * 0.125f;
    ws[WS_CONJW + 2*t + 1] = -sinf(w) * 0.125f;   // conj(W), 1/sqrt(64)
  } else if (t < 4096){
    int i = t - 2048;
    float f = lds1(kF, i, bf);
    ws[WS_F + 2*i]     = cosf(f) * 0.125f;
    ws[WS_F + 2*i + 1] = sinf(f) * 0.125f;
  }
}

// ---- kernel 2: eff -> y output region (fp32 float2) -----------------------
// grid: 64 b x 4 x-chunks x 4 mr-quarters = 1024 blocks, 256 thr.
// Distance-2 software pipeline on the nr loop (4 loads in flight).
__global__ __launch_bounds__(256) void eff_kernel(const void* __restrict__ noise,
                                                  const float* __restrict__ ws,
                                                  float2* __restrict__ y2){
  const bool bf = ws[WS_FLAG] != 0.0f;
  const int bid = blockIdx.x;
  const int b   = bid >> 4;
  const int xc  = (bid >> 2) & 3;
  const int mrq = bid & 3;
  const int x   = (xc << 8) + threadIdx.x;
  const int r0  = mrq << 1;
  float ar[8], ai[8];
#pragma unroll
  for (int j = 0; j < 8; ++j){ ar[j] = 0.f; ai[j] = 0.f; }
  const long base0 = ((long)((b*8 + r0    )*64) << 10) + x;
  const long base1 = ((long)((b*8 + r0 + 1)*64) << 10) + x;
  float2 c0 = ldc(noise, base0, bf);
  float2 c1 = ldc(noise, base1, bf);
  float2 n0 = ldc(noise, base0 + 1024, bf);
  float2 n1 = ldc(noise, base1 + 1024, bf);
#pragma unroll 2
  for (int nr = 0; nr < 64; ++nr){
    const float2 f0 = c0, f1 = c1;
    c0 = n0; c1 = n1;
    if (nr < 62){
      n0 = ldc(noise, base0 + ((long)(nr + 2) << 10), bf);
      n1 = ldc(noise, base1 + ((long)(nr + 2) << 10), bf);
    }
#pragma unroll
    for (int j = 0; j < 8; ++j){
      int mr = (mrq << 3) + j;
      float wr = ws[WS_CONJW + (nr*32 + mr)*2];      // wave-uniform -> s_load
      float wi = ws[WS_CONJW + (nr*32 + mr)*2 + 1];
      float xr = (j < 4) ? f0.x : f1.x;
      float xi = (j < 4) ? f0.y : f1.y;
      ar[j] += wr*xr - wi*xi;
      ai[j] += wr*xi + wi*xr;
    }
  }
  const int mt = x >> 5, s = x & 31;
#pragma unroll
  for (int j = 0; j < 8; ++j){
    int mr = (mrq << 3) + j;
    long o = ((long)((b << 10) + (mt << 5) + mr) << 5) + s;
    y2[o] = make_float2(ar[j], ai[j]);
  }
}

// ---- kernel 3: fused T = W^H H then y += F-contraction + eff --------------
// grid: 64 b x 32 s = 2048 blocks, 256 thr. LDS 64.6 KB -> 2 blocks/CU.
__global__ __launch_bounds__(256) void uy_kernel(const void* __restrict__ H,
                                                 const float* __restrict__ ws,
                                                 float2* __restrict__ y2){
  __shared__ float cw[4096];       // conjW [nr*32+mr]{re,im}     16 KB
  __shared__ float hs[8192];       // H_s   [nr*64+nt]{re,im}     32 KB
  __shared__ float tm[32*65*2];    // T     [mr*65+nt]{re,im}   16.6 KB (pad+1)
  const bool bf = ws[WS_FLAG] != 0.0f;
  const int b = blockIdx.x >> 5;
  const int s = blockIdx.x & 31;
  const int t = threadIdx.x;
  for (int i = t; i < 4096; i += 256) cw[i] = ws[WS_CONJW + i];
#pragma unroll
  for (int k = 0; k < 16; ++k){
    int p  = t + (k << 8);               // p = nr*64 + nt
    long i = ((long)(((b << 6) + (p >> 6)) << 6) + (p & 63)) * 32 + s;
    float2 v = ldc(H, i, bf);
    hs[2*p] = v.x; hs[2*p + 1] = v.y;
  }
  __syncthreads();
  // step A: T[mr, nt] = sum_nr conjW[nr,mr] * H[nr,nt]
  {
    const int mr = t & 31, ntg = t >> 5;
    float tr[8], ti[8];
#pragma unroll
    for (int j = 0; j < 8; ++j){ tr[j] = 0.f; ti[j] = 0.f; }
    for (int nr = 0; nr < 64; ++nr){
      float wr = cw[(nr*32 + mr)*2];
      float wi = cw[(nr*32 + mr)*2 + 1];
#pragma unroll
      for (int j = 0; j < 8; ++j){
        int nt = (ntg << 3) + j;
        float hr = hs[(nr*64 + nt)*2];     // broadcast within half-wave
        float hi = hs[(nr*64 + nt)*2 + 1];
        tr[j] += wr*hr - wi*hi;
        ti[j] += wr*hi + wi*hr;
      }
    }
#pragma unroll
    for (int j = 0; j < 8; ++j){
      int nt = (ntg << 3) + j;
      tm[(mr*65 + nt)*2]     = tr[j];
      tm[(mr*65 + nt)*2 + 1] = ti[j];
    }
  }
  __syncthreads();
  // step B: y[mt,mr] = sum_nt F[nt,mt] * T[mr,nt] + eff (already in y2)
  {
    const int mr = t & 31, mtg = t >> 5;
    float yr[4], yi[4];
#pragma unroll
    for (int j = 0; j < 4; ++j){ yr[j] = 0.f; yi[j] = 0.f; }
    for (int nt = 0; nt < 64; ++nt){
      float Tr = tm[(mr*65 + nt)*2];       // 2-way bank alias (free)
      float Ti = tm[(mr*65 + nt)*2 + 1];
#pragma unroll
      for (int j = 0; j < 4; ++j){
        int mt = (mtg << 2) + j;
        float fr = ws[WS_F + (nt*32 + mt)*2];
        float fi = ws[WS_F + (nt*32 + mt)*2 + 1];
        yr[j] += fr*Tr - fi*Ti;
        yi[j] += fr*Ti + fi*Tr;
      }
    }
#pragma unroll
    for (int j = 0; j < 4; ++j){
      int mt = (mtg << 2) + j;
      long o = ((long)((b << 10) + (mt << 5) + mr) << 5) + s;
      float2 e = y2[o];
      y2[o] = make_float2(yr[j] + e.x, yi[j] + e.y);
    }
  }
}

// ---- kernel 4: fused Phi (v2) ---------------------------------------------
// grid: 512 blocks (8 g-cols each) x 512 thr. Two 256-thread halves (nth)
// each own 32 nt values (disjoint K2 rows -> no duplicate fetch).
// Per half: double-buffered K2 tile in LDS, reg-prefetch next tile while
// computing current -> one barrier per iteration, global latency hidden.
// End: 4-chunk LDS reduction h1->h0 (red aliases dead k2 region), h0 stores.
// LDS: cw 16 KB + k2 (2 halves x 2 buf x 4 KB) 16 KB = 32 KB -> 2 blocks/CU
// (wave-limited: 16 waves/CU = 50% occupancy, vs 25% in v1).
__global__ __launch_bounds__(512, 4) void phi_kernel(const void* __restrict__ K2,
                                                     const float* __restrict__ ws,
                                                     float2* __restrict__ phi2){
  __shared__ float smem[8192];
  float* cw  = smem;            // conjW [nr*32+mr]{re,im}            16 KB
  float* k2s = smem + 4096;     // [nth][buf][nr*8+g]{re,im}          16 KB
  float* red = smem + 4096;     // reduction scratch (aliases k2s)
  const bool bf = ws[WS_FLAG] != 0.0f;
  const int t   = threadIdx.x;
  const int nth = t >> 8;           // nt-half: 0 -> nt 0..31, 1 -> nt 32..63
  const int u   = t & 255;
  const int g   = u & 7;
  const int mr  = u >> 3;
  const int g0  = blockIdx.x << 3;
  const int lr  = u >> 2;           // tile-load row (nr)
  const int lp  = (u & 3) << 1;     // tile-load col pair
  float* myk2 = k2s + nth*2048;

  for (int i = t; i < 4096; i += 512) cw[i] = ws[WS_CONJW + i];

  // prologue: stage tile for first nt of this half into buffer 0
  {
    float4 v0 = ldc2(K2, (long)((nth*32)*64 + lr)*4096 + g0 + lp, bf);
    float* kw = myk2 + (lr*8 + lp)*2;
    kw[0] = v0.x; kw[1] = v0.y; kw[2] = v0.z; kw[3] = v0.w;
  }
  __syncthreads();

  float accr[32], acci[32];
#pragma unroll
  for (int mt = 0; mt < 32; ++mt){ accr[mt] = 0.f; acci[mt] = 0.f; }

  for (int i = 0; i < 32; ++i){
    const int nt = nth*32 + i;
    float4 nx;
    if (i < 31)                      // issue next tile early (latency hides
      nx = ldc2(K2, (long)((nt + 1)*64 + lr)*4096 + g0 + lp, bf);  // under compute)
    const float* kb = myk2 + (i & 1)*1024;
    float sr = 0.f, si = 0.f;
#pragma unroll
    for (int nr = 0; nr < 64; ++nr){
      float2 w = ((const float2*)cw)[nr*32 + mr];    // ds_read_b64
      float2 k = ((const float2*)kb)[nr*8 + g];      // ds_read_b64
      sr += w.x*k.x - w.y*k.y;
      si += w.x*k.y + w.y*k.x;
    }
#pragma unroll
    for (int mt = 0; mt < 32; ++mt){
      float fr = ws[WS_F + (nt*32 + mt)*2];          // wave-uniform -> s_load
      float fi = ws[WS_F + (nt*32 + mt)*2 + 1];
      accr[mt] += fr*sr - fi*si;
      acci[mt] += fr*si + fi*sr;
    }
    if (i < 31){                     // write prefetched tile to other buffer
      float* kw = myk2 + ((i + 1) & 1)*1024 + (lr*8 + lp)*2;
      kw[0] = nx.x; kw[1] = nx.y; kw[2] = nx.z; kw[3] = nx.w;
    }
    __syncthreads();                 // single barrier per iteration
  }

  // cross-half reduction: h1 -> h0, 4 chunks of 8 mt (lane-contiguous layout,
  // conflict-free; red region is dead k2s space, safe after final barrier)
#pragma unroll
  for (int c = 0; c < 4; ++c){
    if (nth == 1){
#pragma unroll
      for (int j = 0; j < 8; ++j){
        red[(2*j    )*256 + u] = accr[c*8 + j];
        red[(2*j + 1)*256 + u] = acci[c*8 + j];
      }
    }
    __syncthreads();
    if (nth == 0){
#pragma unroll
      for (int j = 0; j < 8; ++j){
        accr[c*8 + j] += red[(2*j    )*256 + u];
        acci[c*8 + j] += red[(2*j + 1)*256 + u];
      }
    }
    __syncthreads();
  }

  if (nth == 0){
#pragma unroll
    for (int mt = 0; mt < 32; ++mt){
      long o = (long)((mt << 5) + mr) * 4096 + g0 + g;
      phi2[o] = make_float2(accr[mt], acci[mt]);
    }
  }
}

extern "C" void kernel_launch(void* const* d_in, const int* in_sizes, int n_in,
                              void* d_out, int out_size, void* d_ws, size_t ws_size,
                              hipStream_t stream) {
  const void* H     = d_in[0];   // (64,64,64,32,2)
  const void* noise = d_in[1];   // (64,8,64,1024,2)
  const void* kW    = d_in[2];   // (64,32)
  const void* kF    = d_in[3];   // (64,32)
  const void* K2    = d_in[4];   // (4096,4096,2)
  float* out = (float*)d_out;    // fp32: Phi 8388608 floats, then y 4194304
  float* ws = (float*)d_ws;      // 33 KB used

  float2* phi2 = (float2*)out;                 // complex pairs
  float2* y2   = (float2*)(out + 8388608);

  wf_kernel <<<16,   256, 0, stream>>>(kW, kF, ws);
  eff_kernel<<<1024, 256, 0, stream>>>(noise, ws, y2);
  uy_kernel <<<2048, 256, 0, stream>>>(H, ws, y2);
  phi_kernel<<<512,  512, 0, stream>>>(K2, ws, phi2);
}

// Round 2
// 809.021 us; speedup vs baseline: 5.7381x; 5.7381x over previous
//
// Phi_Layer_joint_opt: factored kron GEMM. fp32 inputs (runtime-sniffed, bf16
// fallback), FP32 outputs (float2 per complex), fp32 internal math.
//
// Nt=Nr=64, Mt=Mr=32, G^2=4096, S=32, B=64, R=8, N_r_RF=4.
// Phi[(mt,mr),g]  = sum_nt F[nt,mt] * ( sum_nr conjW[nr,mr] * K2[nt*64+nr, g] )
// y[b,(mt,mr),s]  = sum_nt F[nt,mt] * T[b,mr,nt,s]  +  eff[b,mr,mt*32+s]
//   T[b,mr,nt,s]  = sum_nr conjW[nr,mr] * H[b,nr,nt,s]      (fused in uy_kernel)
//   eff[b,mr,x]   = sum_nr conjW[nr,mr] * noise[b,mr>>2,nr,x] (written to y out)
//
// ws floats: [0,4096) conjW {re,im}; [4096,8192) F {re,im}; [8192] dtype flag;
//            [16384, 16384+16777216) S[nt][mr][g]{re,im} intermediate (67 MB).
//
// v3 (this round): phi path split into two LDS-free kernels.
//   v2 post-mortem: __launch_bounds__(512,4) forced VGPR=64 -> accr/acci
//   spilled to scratch (FETCH 4.6 GB / WRITE 8.9 GB, 4013 us). Reverted.
//   v1 analysis: inner loop was LDS-pipe-bound (128 ds_read_b64 vs 384 FMA
//   per nt per wave; VALUBusy 47%, conflicts 0). Fix: remove LDS entirely.
//   s_kernel:  lane=g -> K2 loaded once, coalesced, reused across mr from a
//              register; conjW via wave-uniform s_load. 1 load + 128 FMA/nr.
//   p2_kernel: S streamed (L3-resident), F via s_load, acc[mt] in regs.
//   Host checks ws_size; falls back to v1 fused phi if workspace too small.
#include <hip/hip_runtime.h>
#include <hip/hip_bf16.h>

typedef unsigned short u16;
typedef unsigned int u32;

#define WS_CONJW 0
#define WS_F     4096
#define WS_FLAG  8192
#define WS_S     16384                    // float offset of S buffer
#define WS_NEED  ((size_t)(16384 + 64*32*4096*2) * 4)   // 67,174,400 B

__device__ __forceinline__ float bfb2f(u16 b){
  union { u32 u; float f; } v; v.u = ((u32)b) << 16; return v.f;
}
// complex load at pair-index i, dtype selected by wave-uniform flag
__device__ __forceinline__ float2 ldc(const void* p, long i, bool bf){
  if (bf){ ushort2 v = ((const ushort2*)p)[i]; return make_float2(bfb2f(v.x), bfb2f(v.y)); }
  return ((const float2*)p)[i];
}
// two complex (float4) at pair-index i
__device__ __forceinline__ float4 ldc2(const void* p, long i, bool bf){
  if (bf){ ushort4 v = *(const ushort4*)((const u16*)p + 2*i);
           return make_float4(bfb2f(v.x), bfb2f(v.y), bfb2f(v.z), bfb2f(v.w)); }
  return *(const float4*)((const float*)p + 2*i);
}
__device__ __forceinline__ float lds1(const void* p, int i, bool bf){
  return bf ? bfb2f(((const u16*)p)[i]) : ((const float*)p)[i];
}
// Sniff kernel_W storage dtype. bf16 normals: low u16 of each u32 has bf16
// exponent (bits 14:7) ~101..129 for N(0,1). fp32: those bits are uniform
// mantissa bits -> ~16% in range. 64 samples, threshold 48. 256 B in-bounds.
__device__ __forceinline__ bool detect_bf16(const void* kW){
  const u32* p = (const u32*)kW;
  int hits = 0;
  for (int i = 0; i < 64; ++i){
    int e = (p[i] >> 7) & 0xFF;
    hits += (e >= 100 && e <= 140) ? 1 : 0;
  }
  return hits >= 48;
}

// ---- kernel 1: phases -> conjW, F (fp32 in ws) + dtype flag ---------------
__global__ void wf_kernel(const void* __restrict__ kW, const void* __restrict__ kF,
                          float* __restrict__ ws){
  const bool bf = detect_bf16(kW);
  int t = blockIdx.x * 256 + threadIdx.x;
  if (t == 0) ws[WS_FLAG] = bf ? 1.0f : 0.0f;
  if (t < 2048){
    float w = lds1(kW, t, bf);
    ws[WS_CONJW + 2*t]     =  cosf(w) * 0.125f;
    ws[WS_CONJW + 2*t + 1] = -sinf(w) * 0.125f;   // conj(W), 1/sqrt(64)
  } else if (t < 4096){
    int i = t - 2048;
    float f = lds1(kF, i, bf);
    ws[WS_F + 2*i]     = cosf(f) * 0.125f;
    ws[WS_F + 2*i + 1] = sinf(f) * 0.125f;
  }
}

// ---- kernel 2: eff -> y output region (fp32 float2) -----------------------
// grid: 64 b x 4 x-chunks x 4 mr-quarters = 1024 blocks, 256 thr.
// Distance-2 software pipeline on the nr loop (4 loads in flight).
__global__ __launch_bounds__(256) void eff_kernel(const void* __restrict__ noise,
                                                  const float* __restrict__ ws,
                                                  float2* __restrict__ y2){
  const bool bf = ws[WS_FLAG] != 0.0f;
  const int bid = blockIdx.x;
  const int b   = bid >> 4;
  const int xc  = (bid >> 2) & 3;
  const int mrq = bid & 3;
  const int x   = (xc << 8) + threadIdx.x;
  const int r0  = mrq << 1;
  float ar[8], ai[8];
#pragma unroll
  for (int j = 0; j < 8; ++j){ ar[j] = 0.f; ai[j] = 0.f; }
  const long base0 = ((long)((b*8 + r0    )*64) << 10) + x;
  const long base1 = ((long)((b*8 + r0 + 1)*64) << 10) + x;
  float2 c0 = ldc(noise, base0, bf);
  float2 c1 = ldc(noise, base1, bf);
  float2 n0 = ldc(noise, base0 + 1024, bf);
  float2 n1 = ldc(noise, base1 + 1024, bf);
#pragma unroll 2
  for (int nr = 0; nr < 64; ++nr){
    const float2 f0 = c0, f1 = c1;
    c0 = n0; c1 = n1;
    if (nr < 62){
      n0 = ldc(noise, base0 + ((long)(nr + 2) << 10), bf);
      n1 = ldc(noise, base1 + ((long)(nr + 2) << 10), bf);
    }
#pragma unroll
    for (int j = 0; j < 8; ++j){
      int mr = (mrq << 3) + j;
      float wr = ws[WS_CONJW + (nr*32 + mr)*2];      // wave-uniform -> s_load
      float wi = ws[WS_CONJW + (nr*32 + mr)*2 + 1];
      float xr = (j < 4) ? f0.x : f1.x;
      float xi = (j < 4) ? f0.y : f1.y;
      ar[j] += wr*xr - wi*xi;
      ai[j] += wr*xi + wi*xr;
    }
  }
  const int mt = x >> 5, s = x & 31;
#pragma unroll
  for (int j = 0; j < 8; ++j){
    int mr = (mrq << 3) + j;
    long o = ((long)((b << 10) + (mt << 5) + mr) << 5) + s;
    y2[o] = make_float2(ar[j], ai[j]);
  }
}

// ---- kernel 3: fused T = W^H H then y += F-contraction + eff --------------
// grid: 64 b x 32 s = 2048 blocks, 256 thr. LDS 64.6 KB -> 2 blocks/CU.
__global__ __launch_bounds__(256) void uy_kernel(const void* __restrict__ H,
                                                 const float* __restrict__ ws,
                                                 float2* __restrict__ y2){
  __shared__ float cw[4096];       // conjW [nr*32+mr]{re,im}     16 KB
  __shared__ float hs[8192];       // H_s   [nr*64+nt]{re,im}     32 KB
  __shared__ float tm[32*65*2];    // T     [mr*65+nt]{re,im}   16.6 KB (pad+1)
  const bool bf = ws[WS_FLAG] != 0.0f;
  const int b = blockIdx.x >> 5;
  const int s = blockIdx.x & 31;
  const int t = threadIdx.x;
  for (int i = t; i < 4096; i += 256) cw[i] = ws[WS_CONJW + i];
#pragma unroll
  for (int k = 0; k < 16; ++k){
    int p  = t + (k << 8);               // p = nr*64 + nt
    long i = ((long)(((b << 6) + (p >> 6)) << 6) + (p & 63)) * 32 + s;
    float2 v = ldc(H, i, bf);
    hs[2*p] = v.x; hs[2*p + 1] = v.y;
  }
  __syncthreads();
  // step A: T[mr, nt] = sum_nr conjW[nr,mr] * H[nr,nt]
  {
    const int mr = t & 31, ntg = t >> 5;
    float tr[8], ti[8];
#pragma unroll
    for (int j = 0; j < 8; ++j){ tr[j] = 0.f; ti[j] = 0.f; }
    for (int nr = 0; nr < 64; ++nr){
      float wr = cw[(nr*32 + mr)*2];
      float wi = cw[(nr*32 + mr)*2 + 1];
#pragma unroll
      for (int j = 0; j < 8; ++j){
        int nt = (ntg << 3) + j;
        float hr = hs[(nr*64 + nt)*2];     // broadcast within half-wave
        float hi = hs[(nr*64 + nt)*2 + 1];
        tr[j] += wr*hr - wi*hi;
        ti[j] += wr*hi + wi*hr;
      }
    }
#pragma unroll
    for (int j = 0; j < 8; ++j){
      int nt = (ntg << 3) + j;
      tm[(mr*65 + nt)*2]     = tr[j];
      tm[(mr*65 + nt)*2 + 1] = ti[j];
    }
  }
  __syncthreads();
  // step B: y[mt,mr] = sum_nt F[nt,mt] * T[mr,nt] + eff (already in y2)
  {
    const int mr = t & 31, mtg = t >> 5;
    float yr[4], yi[4];
#pragma unroll
    for (int j = 0; j < 4; ++j){ yr[j] = 0.f; yi[j] = 0.f; }
    for (int nt = 0; nt < 64; ++nt){
      float Tr = tm[(mr*65 + nt)*2];       // 2-way bank alias (free)
      float Ti = tm[(mr*65 + nt)*2 + 1];
#pragma unroll
      for (int j = 0; j < 4; ++j){
        int mt = (mtg << 2) + j;
        float fr = ws[WS_F + (nt*32 + mt)*2];
        float fi = ws[WS_F + (nt*32 + mt)*2 + 1];
        yr[j] += fr*Tr - fi*Ti;
        yi[j] += fr*Ti + fi*Tr;
      }
    }
#pragma unroll
    for (int j = 0; j < 4; ++j){
      int mt = (mtg << 2) + j;
      long o = ((long)((b << 10) + (mt << 5) + mr) << 5) + s;
      float2 e = y2[o];
      y2[o] = make_float2(yr[j] + e.x, yi[j] + e.y);
    }
  }
}

// ---- kernel 4a: S[nt][mr][g] = sum_nr conjW[nr,mr] * K2[nt*64+nr, g] ------
// grid: 64 nt x 16 g-chunks = 1024 blocks, 256 thr. Zero LDS.
// lane = g: K2 element loaded ONCE (coalesced 8B/lane) into a register and
// reused across all 32 mr; conjW indices wave-uniform -> s_load (scalar pipe).
// Inner loop per nr: 1 global load + 128 FMA. acc = 64 fp32/thread.
__global__ __launch_bounds__(256) void s_kernel(const void* __restrict__ K2,
                                                const float* __restrict__ ws,
                                                float2* __restrict__ S){
  const bool bf = ws[WS_FLAG] != 0.0f;
  const int nt = blockIdx.x >> 4;
  const int g  = ((blockIdx.x & 15) << 8) + threadIdx.x;
  const long base0 = ((long)nt << 18) + g;        // (nt*64 + 0)*4096 + g
  float accr[32], acci[32];
#pragma unroll
  for (int mr = 0; mr < 32; ++mr){ accr[mr] = 0.f; acci[mr] = 0.f; }
  float2 c  = ldc(K2, base0, bf);                 // distance-2 pipeline
  float2 nx = ldc(K2, base0 + 4096, bf);
  for (int nr = 0; nr < 64; ++nr){
    const float2 k = c; c = nx;
    if (nr < 62) nx = ldc(K2, base0 + ((long)(nr + 2) << 12), bf);
#pragma unroll
    for (int mr = 0; mr < 32; ++mr){
      float wr = ws[WS_CONJW + (nr*32 + mr)*2];   // wave-uniform -> s_load
      float wi = ws[WS_CONJW + (nr*32 + mr)*2 + 1];
      accr[mr] += wr*k.x - wi*k.y;
      acci[mr] += wr*k.y + wi*k.x;
    }
  }
#pragma unroll
  for (int mr = 0; mr < 32; ++mr)
    S[((long)(nt*32 + mr) << 12) + g] = make_float2(accr[mr], acci[mr]);
}

// ---- kernel 4b: Phi[(mt,mr),g] = sum_nt F[nt,mt] * S[nt][mr][g] -----------
// grid: 32 mr x 16 g-chunks = 512 blocks, 256 thr. Zero LDS.
// S streamed (fits L3); F wave-uniform -> s_load. 1 load + 128 FMA per nt.
__global__ __launch_bounds__(256) void p2_kernel(const float2* __restrict__ S,
                                                 const float* __restrict__ ws,
                                                 float2* __restrict__ phi2){
  const int mr = blockIdx.x >> 4;
  const int g  = ((blockIdx.x & 15) << 8) + threadIdx.x;
  const long base0 = ((long)mr << 12) + g;        // (0*32 + mr)*4096 + g
  float accr[32], acci[32];
#pragma unroll
  for (int mt = 0; mt < 32; ++mt){ accr[mt] = 0.f; acci[mt] = 0.f; }
  float2 c  = S[base0];                           // distance-2 pipeline
  float2 nx = S[base0 + (1L << 17)];
  for (int nt = 0; nt < 64; ++nt){
    const float2 s = c; c = nx;
    if (nt < 62) nx = S[base0 + ((long)(nt + 2) << 17)];
#pragma unroll
    for (int mt = 0; mt < 32; ++mt){
      float fr = ws[WS_F + (nt*32 + mt)*2];       // wave-uniform -> s_load
      float fi = ws[WS_F + (nt*32 + mt)*2 + 1];
      accr[mt] += fr*s.x - fi*s.y;
      acci[mt] += fr*s.y + fi*s.x;
    }
  }
#pragma unroll
  for (int mt = 0; mt < 32; ++mt){
    long o = (long)((mt << 5) + mr) * 4096 + g;
    phi2[o] = make_float2(accr[mt], acci[mt]);
  }
}

// ---- kernel 4 fallback: fused Phi (v1, known-good) ------------------------
// Used only if ws_size can't hold the 67 MB S intermediate.
__global__ __launch_bounds__(256) void phi_fallback(const void* __restrict__ K2,
                                                    const float* __restrict__ ws,
                                                    float2* __restrict__ phi2){
  __shared__ float cw[4096];     // conjW  16 KB
  __shared__ float k2s[1024];    // K2 tile [nr*8+g]{re,im}  4 KB
  const bool bf = ws[WS_FLAG] != 0.0f;
  const int t = threadIdx.x;
  for (int i = t; i < 4096; i += 256) cw[i] = ws[WS_CONJW + i];
  const int g  = t & 7;
  const int mr = t >> 3;
  const int g0 = blockIdx.x << 3;
  const int lr = t >> 2;            // tile-load row (nr)
  const int lp = (t & 3) << 1;      // tile-load col pair
  float accr[32], acci[32];
#pragma unroll
  for (int mt = 0; mt < 32; ++mt){ accr[mt] = 0.f; acci[mt] = 0.f; }
  __syncthreads();
  for (int nt = 0; nt < 64; ++nt){
    long base = (long)(nt*64 + lr) * 4096 + g0 + lp;   // pair index
    float4 vv = ldc2(K2, base, bf);
    k2s[(lr*8 + lp)*2    ] = vv.x;
    k2s[(lr*8 + lp)*2 + 1] = vv.y;
    k2s[(lr*8 + lp)*2 + 2] = vv.z;
    k2s[(lr*8 + lp)*2 + 3] = vv.w;
    __syncthreads();
    float sr = 0.f, si = 0.f;
#pragma unroll
    for (int nr = 0; nr < 64; ++nr){
      float wr = cw[(nr*32 + mr)*2];
      float wi = cw[(nr*32 + mr)*2 + 1];
      float kr = k2s[(nr*8 + g)*2];
      float ki = k2s[(nr*8 + g)*2 + 1];
      sr += wr*kr - wi*ki;
      si += wr*ki + wi*kr;
    }
#pragma unroll
    for (int mt = 0; mt < 32; ++mt){
      float fr = ws[WS_F + (nt*32 + mt)*2];          // wave-uniform -> s_load
      float fi = ws[WS_F + (nt*32 + mt)*2 + 1];
      accr[mt] += fr*sr - fi*si;
      acci[mt] += fr*si + fi*sr;
    }
    __syncthreads();
  }
#pragma unroll
  for (int mt = 0; mt < 32; ++mt){
    long o = (long)((mt << 5) + mr) * 4096 + g0 + g;
    phi2[o] = make_float2(accr[mt], acci[mt]);
  }
}

extern "C" void kernel_launch(void* const* d_in, const int* in_sizes, int n_in,
                              void* d_out, int out_size, void* d_ws, size_t ws_size,
                              hipStream_t stream) {
  const void* H     = d_in[0];   // (64,64,64,32,2)
  const void* noise = d_in[1];   // (64,8,64,1024,2)
  const void* kW    = d_in[2];   // (64,32)
  const void* kF    = d_in[3];   // (64,32)
  const void* K2    = d_in[4];   // (4096,4096,2)
  float* out = (float*)d_out;    // fp32: Phi 8388608 floats, then y 4194304
  float* ws = (float*)d_ws;

  float2* phi2 = (float2*)out;                 // complex pairs
  float2* y2   = (float2*)(out + 8388608);

  wf_kernel <<<16,   256, 0, stream>>>(kW, kF, ws);
  eff_kernel<<<1024, 256, 0, stream>>>(noise, ws, y2);
  uy_kernel <<<2048, 256, 0, stream>>>(H, ws, y2);
  if (ws_size >= WS_NEED){
    float2* S = (float2*)(ws + WS_S);
    s_kernel <<<1024, 256, 0, stream>>>(K2, ws, S);
    p2_kernel<<<512,  256, 0, stream>>>(S, ws, phi2);
  } else {
    phi_fallback<<<512, 256, 0, stream>>>(K2, ws, phi2);
  }
}